// Round 1
// 9403.286 us; speedup vs baseline: 1.0657x; 1.0657x over previous
//
#include <hip/hip_runtime.h>
#include <hip/hip_bf16.h>

#define Bb 32
#define Tt 1024
#define Dd 768
#define Hh 768
#define NGRP 2       // independent batch groups (no cross-group sync)
#define BPG 96       // blocks per group
#define GB  16       // batches per group
#define CPB 8        // h-columns per block (96*8 = 768)
#define NTHREADS 192 // 3 waves = 3 N-tiles exactly

#define NWELE ((size_t)6 * Hh * Dd)   // W_in elements
#define NSELE ((size_t)5 * Hh * Hh)   // W_s elements
#define WS_FLAGS 4096
#define WS_HB    8192
#define HBSZ     (GB * Hh * 2)        // 24576 B per h buffer
#define WS_WGT   (WS_HB + 4 * HBSZ)   // 2 groups x 2 phase buffers
#define WS_NEED  (WS_WGT + (NWELE + NSELE) * 2)

typedef short short8 __attribute__((ext_vector_type(8)));
typedef float f4 __attribute__((ext_vector_type(4)));

__device__ __forceinline__ float bf2f(ushort u) {
    unsigned x = (unsigned)u << 16;
    return __builtin_bit_cast(float, x);
}
__device__ __forceinline__ ushort f2bf(float f) {
    unsigned u = __builtin_bit_cast(unsigned, f);
    return (ushort)((u + 0x7fffu + ((u >> 16) & 1u)) >> 16);
}
__device__ __forceinline__ float sigm(float x) { return 1.0f / (1.0f + __expf(-x)); }
__device__ __forceinline__ float tanh_(float x) {
    float e = __expf(2.0f * x);
    return 1.0f - 2.0f / (e + 1.0f);
}

// nb[t] = number of active batches at step t (lengths sorted descending)
__global__ void prep_nb(const int* __restrict__ len, int* __restrict__ nbArr) {
    int t = blockIdx.x * 256 + threadIdx.x;
    if (t < Tt) {
        int c = 0;
#pragma unroll
        for (int b = 0; b < Bb; ++b) c += (len[b] > t) ? 1 : 0;
        nbArr[t] = c;
    }
}

// Convert (or copy) W_in and W_s into a packed bf16 image in ws.
__global__ void conv_w(const void* __restrict__ Win, const void* __restrict__ Ws,
                       const void* __restrict__ bs, ushort* __restrict__ wOut) {
    const bool isbf = (((const unsigned*)bs)[384] != 0u);
    size_t i = ((size_t)blockIdx.x * 256 + threadIdx.x) * 8;
    if (i >= NWELE + NSELE) return;
    const void* src = (i < NWELE) ? Win : Ws;
    size_t off = (i < NWELE) ? i : (i - NWELE);
    if (isbf) {
        *(uint4*)(wOut + i) = *(const uint4*)((const ushort*)src + off);
    } else {
        const f4* s = (const f4*)((const float*)src + off);
        f4 a = s[0], c = s[1];
        uint4 v;
        v.x = (unsigned)f2bf(a[0]) | ((unsigned)f2bf(a[1]) << 16);
        v.y = (unsigned)f2bf(a[2]) | ((unsigned)f2bf(a[3]) << 16);
        v.z = (unsigned)f2bf(c[0]) | ((unsigned)f2bf(c[1]) << 16);
        v.w = (unsigned)f2bf(c[2]) | ((unsigned)f2bf(c[3]) << 16);
        *(uint4*)(wOut + i) = v;
    }
}

// Persistent fused LSTM, batch-grouped: 2 independent groups x 96 blocks x 16
// batches. Block owns 8 h-cols; per step: x-GEMM (W_in streamed from L2,
// overlaps flag propagation) + ps-GEMM with A-fragments loaded DIRECTLY from
// the global h buffer (publisher chunk layout == MFMA A-fragment layout, so
// no LDS staging hop); combine publishes via intra-wave shfl gather.
// 3 barriers/step (was 6).
__global__ __launch_bounds__(NTHREADS, 1) void lstm_main(
    const void* __restrict__ inp, const void* __restrict__ bin,
    const void* __restrict__ bs, const int* __restrict__ len,
    void* __restrict__ y, const int* __restrict__ nbArr,
    unsigned* flags, ushort* hbAll, const ushort* __restrict__ wbf)
{
    __shared__ ushort wsL[48 * 776];     // W_s slice, rows 40..47 zero (74.5 KB)
    __shared__ ushort hA[GB * 776];      // staged x K-operand only (24.8 KB)
    __shared__ float accT[3][16][16];    // 3 N-tile results (3 KB)

    const bool isbf = (((const unsigned*)bs)[384] != 0u);

    const int tid  = threadIdx.x;
    const int lane = tid & 63;
    const int wave = tid >> 6;           // 0..2 = N-tile
    const int g    = blockIdx.x & 1;     // group
    const int w    = blockIdx.x >> 1;    // block index within group, 0..95
    const int n0   = w * CPB;

    // --- W_s slice into LDS: zero all 48 rows, fill rows 0..39 ---
    for (int i = tid; i < 48 * 776 / 8; i += NTHREADS)
        *(uint4*)&wsL[i * 8] = uint4{0u, 0u, 0u, 0u};
    const ushort* wbfS = wbf + NWELE;
    __syncthreads();
    for (int i = tid; i < 40 * 96; i += NTHREADS) {
        int c = i / 96, ch = i - c * 96;
        *(uint4*)&wsL[c * 776 + ch * 8] =
            *(const uint4*)(wbfS + ((size_t)((c >> 3) * Hh + n0 + (c & 7))) * Hh + ch * 8);
    }

    // --- per-thread combine constants ---
    float B0 = 0, B1 = 0, B2 = 0, B3 = 0, B4 = 0, B5 = 0, cReg = 0.0f;
    int lenb = 0;
    if (tid < 128) {
        int j = tid & 7, n = n0 + j;
        if (isbf) {
            const ushort* bi = (const ushort*)bin; const ushort* bsp = (const ushort*)bs;
            B0 = bf2f(bi[0 * Hh + n]) + bf2f(bsp[0 * Hh + n]);
            B1 = bf2f(bi[1 * Hh + n]) + bf2f(bsp[1 * Hh + n]);
            B2 = bf2f(bi[2 * Hh + n]) + bf2f(bsp[2 * Hh + n]);
            B3 = bf2f(bi[3 * Hh + n]) + bf2f(bsp[3 * Hh + n]);
            B4 = bf2f(bi[4 * Hh + n]) + bf2f(bsp[4 * Hh + n]);
            B5 = bf2f(bi[5 * Hh + n]);
        } else {
            const float* bi = (const float*)bin; const float* bsp = (const float*)bs;
            B0 = bi[0 * Hh + n] + bsp[0 * Hh + n];
            B1 = bi[1 * Hh + n] + bsp[1 * Hh + n];
            B2 = bi[2 * Hh + n] + bsp[2 * Hh + n];
            B3 = bi[3 * Hh + n] + bsp[3 * Hh + n];
            B4 = bi[4 * Hh + n] + bsp[4 * Hh + n];
            B5 = bi[5 * Hh + n];
        }
        lenb = len[g * GB + (tid >> 3)];
    }

    // --- MFMA fragment addressing ---
    // A (x-half): lane holds A[m=lane&15][k=(lane>>4)*8+j]; M=16 (all group batches)
    const int kq = (lane >> 4) << 3;
    const ushort* aP = &hA[(lane & 15) * 776 + kq];
    // A (h-half): DIRECT from global h buffer. Chunk layout hb[w2*128 + b*8 + c]
    // == fragment: u64 offset (4*kb + (lane>>4))*32 + (lane&15)*2.
    const int aoff = ((lane >> 4) * 32) + ((lane & 15) * 2);
    // B (x-half): W_in row for col cc = wave*16+(lane&15): gate=cc>>3, j=cc&7
    const int cc = wave * 16 + (lane & 15);
    const uint4* bPx = (const uint4*)(wbf + ((size_t)((cc >> 3) * Hh + n0 + (cc & 7))) * Dd + kq);
    // B (h-half): from LDS W_s slice, row cc (rows 40..47 are zeros)
    const ushort* wsP = &wsL[cc * 776 + kq];

    unsigned* flg = flags + g * 128;
    ushort* hb[2] = {hbAll + (g * 2 + 0) * (HBSZ / 2),
                     hbAll + (g * 2 + 1) * (HBSZ / 2)};
    int p = 0;
    long gmax = (1L << 22);
    __syncthreads();

    int tDone = Tt;
    for (int t = 0; t < Tt; ++t) {
        int nbg = nbArr[t] - g * GB;
        nbg = nbg < 0 ? 0 : (nbg > GB ? GB : nbg);
        if (nbg == 0) { tDone = t; break; }

        // ---- stage x_t (16 rows, convert to bf16) ----
        if (isbf) {
            const ushort* xi = (const ushort*)inp;
            for (int i = tid; i < GB * 96; i += NTHREADS) {
                int row = i / 96, c8 = i - row * 96;
                *(uint4*)&hA[row * 776 + c8 * 8] =
                    *((const uint4*)(xi + ((size_t)(g * GB + row) * Tt + t) * Dd) + c8);
            }
        } else {
            const float* xf = (const float*)inp;
            for (int i = tid; i < GB * 96; i += NTHREADS) {
                int row = i / 96, c8 = i - row * 96;
                const f4* s = (const f4*)(xf + ((size_t)(g * GB + row) * Tt + t) * Dd + c8 * 8);
                f4 a = s[0], c = s[1];
                uint4 v;
                v.x = (unsigned)f2bf(a[0]) | ((unsigned)f2bf(a[1]) << 16);
                v.y = (unsigned)f2bf(a[2]) | ((unsigned)f2bf(a[3]) << 16);
                v.z = (unsigned)f2bf(c[0]) | ((unsigned)f2bf(c[1]) << 16);
                v.w = (unsigned)f2bf(c[2]) | ((unsigned)f2bf(c[3]) << 16);
                *(uint4*)&hA[row * 776 + c8 * 8] = v;
            }
        }
        __syncthreads();   // (1) hA ready; also drains previous y stores

        // ---- x-GEMM (W_in from L2; overlaps flag propagation) ----
        f4 acc0 = {0, 0, 0, 0}, acc1 = {0, 0, 0, 0};
#pragma unroll
        for (int kb = 0; kb < 24; ++kb) {
            short8 a = __builtin_bit_cast(short8, *(const uint4*)(aP + kb * 32));
            short8 b = __builtin_bit_cast(short8, bPx[kb * 4]);
            if (kb & 1) acc1 = __builtin_amdgcn_mfma_f32_16x16x32_bf16(a, b, acc1, 0, 0, 0);
            else        acc0 = __builtin_amdgcn_mfma_f32_16x16x32_bf16(a, b, acc0, 0, 0, 0);
        }

        // ---- per-wave group wait: poll 96 flags (agent scope, backoff) ----
        if (t > 0) {
            const unsigned target = (unsigned)t;
            long guard = 0;
            for (;;) {
                unsigned f0 = __hip_atomic_load(flg + lane, __ATOMIC_RELAXED,
                                                __HIP_MEMORY_SCOPE_AGENT);
                unsigned f1 = __hip_atomic_load(flg + 32 + lane, __ATOMIC_RELAXED,
                                                __HIP_MEMORY_SCOPE_AGENT);
                bool ok = (f0 >= target) && (f1 >= target);
                if (__all(ok)) break;
                if (++guard > gmax) break;
                __builtin_amdgcn_s_sleep(1);
            }
        }
        __asm__ volatile("" ::: "memory");

        // ---- ps-GEMM: A-fragments straight from the global h buffer ----
        {
            const unsigned long long* aB = (const unsigned long long*)hb[p];
#pragma unroll
            for (int kb = 0; kb < 24; ++kb) {
                unsigned long long v0 = __hip_atomic_load(aB + kb * 128 + aoff,
                                                          __ATOMIC_RELAXED,
                                                          __HIP_MEMORY_SCOPE_AGENT);
                unsigned long long v1 = __hip_atomic_load(aB + kb * 128 + aoff + 1,
                                                          __ATOMIC_RELAXED,
                                                          __HIP_MEMORY_SCOPE_AGENT);
                short8 a;
                __builtin_memcpy(&a, &v0, 8);
                __builtin_memcpy((char*)&a + 8, &v1, 8);
                short8 b = __builtin_bit_cast(short8, *(const uint4*)(wsP + kb * 32));
                if (kb & 1) acc1 = __builtin_amdgcn_mfma_f32_16x16x32_bf16(a, b, acc1, 0, 0, 0);
                else        acc0 = __builtin_amdgcn_mfma_f32_16x16x32_bf16(a, b, acc0, 0, 0, 0);
            }
        }
        {
            f4 s = acc0 + acc1;
            int r0 = (lane >> 4) * 4, col = lane & 15;
#pragma unroll
            for (int i = 0; i < 4; ++i) accT[wave][r0 + i][col] = s[i];
        }
        __syncthreads();   // (2) accT ready

        // ---- combine + direct publish (shfl-gather, no LDS handoff) ----
        float outv = 0.0f; bool act = false;
        if (tid < 128) {
            int b = tid >> 3, j = tid & 7;
            float v0 = accT[(0 * 8 + j) >> 4][b][(0 * 8 + j) & 15];
            float v1 = accT[(1 * 8 + j) >> 4][b][(1 * 8 + j) & 15];
            float v2 = accT[(2 * 8 + j) >> 4][b][(2 * 8 + j) & 15];
            float v3 = accT[(3 * 8 + j) >> 4][b][(3 * 8 + j) & 15];
            float v4 = accT[(4 * 8 + j) >> 4][b][(4 * 8 + j) & 15];
            float v5 = accT[(5 * 8 + j) >> 4][b][(5 * 8 + j) & 15];
            float ii = sigm(v0 + B0);
            float ff = sigm(v1 + B1);
            float gg = tanh_(v2 + B2);
            float oo = sigm(v3 + B3);
            float hw = sigm(v4 + B4);
            float p5 = v5 + B5;
            float cn = ii * gg + ff * cReg;
            outv = oo * tanh_(cn);
            outv = hw * outv + (1.0f - hw) * p5;
            act = t < lenb;
            if (act) cReg = cn;

            // gather 4 bf16 from the 4-lane subgroup; lanes j in {0,4} publish 8 B
            unsigned myv = (unsigned)f2bf(outv);
            int lane6 = tid & 63;
            int g0 = lane6 & ~3;
            unsigned a0 = (unsigned)__shfl((int)myv, g0 + 0);
            unsigned a1 = (unsigned)__shfl((int)myv, g0 + 1);
            unsigned a2 = (unsigned)__shfl((int)myv, g0 + 2);
            unsigned a3 = (unsigned)__shfl((int)myv, g0 + 3);
            if ((lane6 & 3) == 0 && act) {
                unsigned long long vv = (unsigned long long)(a0 & 0xffffu)
                    | ((unsigned long long)(a1 & 0xffffu) << 16)
                    | ((unsigned long long)(a2 & 0xffffu) << 32)
                    | ((unsigned long long)(a3 & 0xffffu) << 48);
                __hip_atomic_store(
                    (unsigned long long*)(hb[p ^ 1] + w * 128 + b * 8 + j),
                    vv, __ATOMIC_RELAXED, __HIP_MEMORY_SCOPE_AGENT);
            }
        }
        __syncthreads();   // (3) drains h stores (vmcnt(0)) before flag
        if (tid == 0)
            __hip_atomic_store(flg + w, (unsigned)(t + 1),
                               __ATOMIC_RELAXED, __HIP_MEMORY_SCOPE_AGENT);

        // ---- y write AFTER the flag (HBM store ack off the critical path) ----
        if (tid < 128) {
            int b = tid >> 3, j = tid & 7;
            size_t oi = ((size_t)(g * GB + b) * Tt + t) * Hh + n0 + j;
            if (isbf) ((ushort*)y)[oi] = act ? f2bf(outv) : (ushort)0;
            else      ((float*)y)[oi]  = act ? outv : 0.0f;
        }
        p ^= 1;
    }

    // ---- tail: group finished -> zero its remaining y cells ----
    if (tid < 128) {
        int b = tid >> 3, j = tid & 7;
        for (int t = tDone; t < Tt; ++t) {
            size_t oi = ((size_t)(g * GB + b) * Tt + t) * Hh + n0 + j;
            if (isbf) ((ushort*)y)[oi] = 0; else ((float*)y)[oi] = 0.0f;
        }
    }
}

extern "C" void kernel_launch(void* const* d_in, const int* in_sizes, int n_in,
                              void* d_out, int out_size, void* d_ws, size_t ws_size,
                              hipStream_t stream) {
    const void* inp = d_in[0];
    const void* Win = d_in[1];
    const void* bin = d_in[2];
    const void* Ws  = d_in[3];
    const void* bs  = d_in[4];
    const int*  len = (const int*)d_in[5];

    if (ws_size < WS_NEED) return;  // evidence: >=26.6 MB granted in R3; need 13.1 MB

    char* ws = (char*)d_ws;
    int* nbArr      = (int*)ws;
    unsigned* flags = (unsigned*)(ws + WS_FLAGS);
    ushort* hbAll   = (ushort*)(ws + WS_HB);
    ushort* wbf     = (ushort*)(ws + WS_WGT);

    hipMemsetAsync(d_ws, 0, WS_WGT, stream);   // nbArr/flags/h buffers = 0
    prep_nb<<<4, 256, 0, stream>>>(len, nbArr);
    conv_w<<<3168, 256, 0, stream>>>(Win, Ws, bs, wbf);
    lstm_main<<<NGRP * BPG, NTHREADS, 0, stream>>>(inp, bin, bs, len, d_out,
                                                   nbArr, flags, hbAll, wbf);
}